// Round 2
// baseline (3990.983 us; speedup 1.0000x reference)
//
#include <hip/hip_runtime.h>
#include <hip/hip_bf16.h>
#include <stdint.h>

#define VOCAB 32000
#define HID 512
#define NB 8
#define SEQ 512
#define NG 1536
#define LN_EPS 1e-5f
#define GRU_WGS 32
#define GRU_SPIN_BUDGET (1 << 23)

typedef short bf16x8 __attribute__((ext_vector_type(8)));
typedef float f32x4 __attribute__((ext_vector_type(4)));

__device__ __forceinline__ unsigned short f2bf(float f) {
  union { float f; uint32_t u; } c; c.f = f;
  return (unsigned short)((c.u + 0x7fffu + ((c.u >> 16) & 1u)) >> 16);
}

// ---------------- init workspace (every launch: h_state bufs=0, flags=0) ----
__global__ void init_ws_kernel(unsigned short* h_state, int* flags) {
  int i = blockIdx.x * 256 + threadIdx.x;
  if (i < 2 * 16 * HID) h_state[i] = 0;
  if (i < GRU_WGS * 16) flags[i] = 0;
}

// ---------------- fp32 -> bf16 bulk convert ---------------------------------
__global__ void conv_bf16_kernel(const float* __restrict__ in,
                                 unsigned short* __restrict__ out, int n4) {
  int i = blockIdx.x * 256 + threadIdx.x;
  if (i >= n4) return;
  const float4 v = ((const float4*)in)[i];
  ushort4 o;
  o.x = f2bf(v.x); o.y = f2bf(v.y); o.z = f2bf(v.z); o.w = f2bf(v.w);
  ((ushort4*)out)[i] = o;
}

// ---------------- embedding gather -> bf16 A matrix [4096][512] -------------
__global__ void embed_kernel(const int* __restrict__ ids,
                             const float* __restrict__ emb,
                             unsigned short* __restrict__ out) {
  int row = blockIdx.x;
  int id = ids[row];
  int c = threadIdx.x * 2;
  const float2 v = *(const float2*)(emb + (size_t)id * HID + c);
  ushort2 o; o.x = f2bf(v.x); o.y = f2bf(v.y);
  *(ushort2*)(out + (size_t)row * HID + c) = o;
}

// ---------------- bf16 GEMM: C[M][N] = A[M][K] * B[N][K]^T + bias -----------
// m97 structure: 128x128 tile, BK=32, 4 waves (2x2), 4x4 16x16x32 frags/wave,
// global_load_lds width=16 staging, XCD-chunked block swizzle (nwg%8==0).
#define BM 128
#define BN 128
#define BK 32

__global__ __launch_bounds__(256, 2) void gemm_bt_kernel(
    const unsigned short* __restrict__ A, const unsigned short* __restrict__ B,
    const float* __restrict__ bias, float* __restrict__ C, int N, int nbn) {
  __shared__ unsigned short a_lds[BM * BK];
  __shared__ unsigned short b_lds[BN * BK];
  const int nwg = gridDim.x;
  const int chunk = nwg >> 3;
  const int bid = blockIdx.x;
  const int sw = (bid & 7) * chunk + (bid >> 3);
  const int bm = sw / nbn, bn = sw % nbn;
  const int tid = threadIdx.x;
  const int lane = tid & 63, wid = tid >> 6;
  const int wm = wid >> 1, wn = wid & 1;

  f32x4 acc[4][4] = {};

  for (int kt = 0; kt < HID / BK; ++kt) {
    __syncthreads();
#pragma unroll
    for (int p = 0; p < 2; ++p) {
      const int flat = (p * 256 + tid) * 16;  // byte offset in 8KB tile
      const int row = flat >> 6;              // 64B per row (32 bf16)
      const int kb = flat & 63;
      const char* ga =
          (const char*)(A + ((size_t)(bm * BM + row) * HID + kt * BK)) + kb;
      const char* gb =
          (const char*)(B + ((size_t)(bn * BN + row) * HID + kt * BK)) + kb;
      char* la = (char*)a_lds + (size_t)(p * 256 + wid * 64) * 16;
      char* lb = (char*)b_lds + (size_t)(p * 256 + wid * 64) * 16;
      __builtin_amdgcn_global_load_lds(
          (const __attribute__((address_space(1))) void*)ga,
          (__attribute__((address_space(3))) void*)la, 16, 0, 0);
      __builtin_amdgcn_global_load_lds(
          (const __attribute__((address_space(1))) void*)gb,
          (__attribute__((address_space(3))) void*)lb, 16, 0, 0);
    }
    __syncthreads();
    bf16x8 af[4], bfr[4];
#pragma unroll
    for (int i = 0; i < 4; ++i) {
      af[i] = *(const bf16x8*)(a_lds + (wm * 64 + i * 16 + (lane & 15)) * BK +
                               (lane >> 4) * 8);
      bfr[i] = *(const bf16x8*)(b_lds + (wn * 64 + i * 16 + (lane & 15)) * BK +
                                (lane >> 4) * 8);
    }
#pragma unroll
    for (int i = 0; i < 4; ++i)
#pragma unroll
      for (int j = 0; j < 4; ++j)
        acc[i][j] =
            __builtin_amdgcn_mfma_f32_16x16x32_bf16(af[i], bfr[j], acc[i][j], 0, 0, 0);
  }
#pragma unroll
  for (int i = 0; i < 4; ++i) {
    const int mrow = bm * BM + wm * 64 + i * 16 + (lane >> 4) * 4;
#pragma unroll
    for (int j = 0; j < 4; ++j) {
      const int col = bn * BN + wn * 64 + j * 16 + (lane & 15);
      const float bv = bias[col];
#pragma unroll
      for (int r = 0; r < 4; ++r)
        C[(size_t)(mrow + r) * N + col] = acc[i][j][r] + bv;
    }
  }
}

// ---------------- persistent GRU scan ---------------------------------------
// 32 WGs x 192 threads (3 waves), regular launch (32 WGs on 256 CUs are
// de-facto co-resident; bounded spin guarantees termination regardless).
// WG w owns h indices [w*16, w*16+16). Wave g (=gate r/z/n) holds its 16
// w_hh rows as bf16 MFMA B-frags in regs. h_state is DOUBLE-BUFFERED
// (read buf[t&1], write buf[(t+1)&1]) to eliminate the read/overwrite race.
__global__ __launch_bounds__(192, 1) void gru_kernel(
    const float* __restrict__ xg, const float* __restrict__ w_hh,
    const float* __restrict__ b_hh, float* __restrict__ hs,
    unsigned short* h_state, int* flags) {
  const int wid = blockIdx.x;
  const int tid = threadIdx.x;
  const int lane = tid & 63;
  const int g = tid >> 6;

  __shared__ float hg_lds[3 * 128];
  __shared__ float h_my[128];
  __shared__ float bhh_lds[48];

  // pack weights into MFMA B-fragments (registers), once
  bf16x8 wf[16];
  {
    const int row = g * HID + wid * 16 + (lane & 15);
    const float* wr = w_hh + (size_t)row * HID + (lane >> 4) * 8;
#pragma unroll
    for (int kk = 0; kk < 16; ++kk) {
      float4 f0 = *(const float4*)(wr + kk * 32);
      float4 f1 = *(const float4*)(wr + kk * 32 + 4);
      bf16x8 v;
      v[0] = (short)f2bf(f0.x); v[1] = (short)f2bf(f0.y);
      v[2] = (short)f2bf(f0.z); v[3] = (short)f2bf(f0.w);
      v[4] = (short)f2bf(f1.x); v[5] = (short)f2bf(f1.y);
      v[6] = (short)f2bf(f1.z); v[7] = (short)f2bf(f1.w);
      wf[kk] = v;
    }
  }
  if (tid < 48) bhh_lds[tid] = b_hh[(tid >> 4) * HID + wid * 16 + (tid & 15)];
  if (tid < 128) h_my[tid] = 0.f;
  __syncthreads();

  const int abase = (lane & 15) * HID + (lane >> 4) * 8;  // bf16-elem index
  const int myflag = (lane & 31) * 16;
  const int b8 = tid >> 4, n16 = tid & 15;
  const size_t xoff0 = (size_t)b8 * SEQ * NG + wid * 16 + n16;

  float xr = 0.f, xz = 0.f, xn = 0.f;
  if (tid < 128) {
    xr = xg[xoff0];
    xz = xg[xoff0 + HID];
    xn = xg[xoff0 + 2 * HID];
  }

  int budget = GRU_SPIN_BUDGET;

  for (int t = 0; t < SEQ; ++t) {
    const unsigned short* rd = h_state + (size_t)(t & 1) * (16 * HID);
    unsigned short* wr_ = h_state + (size_t)((t + 1) & 1) * (16 * HID);

    // issue all 32 h-state loads (independent), then the MFMA chain
    uint64_t hb[32];
#pragma unroll
    for (int kk = 0; kk < 16; ++kk) {
      const uint64_t* ap = (const uint64_t*)(rd + abase + kk * 32);
      hb[2 * kk] =
          __hip_atomic_load(ap, __ATOMIC_RELAXED, __HIP_MEMORY_SCOPE_AGENT);
      hb[2 * kk + 1] =
          __hip_atomic_load(ap + 1, __ATOMIC_RELAXED, __HIP_MEMORY_SCOPE_AGENT);
    }
    f32x4 acc = {0.f, 0.f, 0.f, 0.f};
#pragma unroll
    for (int kk = 0; kk < 16; ++kk) {
      union { uint64_t u[2]; bf16x8 v; } cv;
      cv.u[0] = hb[2 * kk]; cv.u[1] = hb[2 * kk + 1];
      acc = __builtin_amdgcn_mfma_f32_16x16x32_bf16(cv.v, wf[kk], acc, 0, 0, 0);
    }
    if (lane < 32) {  // real batches m=0..7 live in lanes 0..31
      const int m0 = (lane >> 4) * 4;
#pragma unroll
      for (int r = 0; r < 4; ++r)
        hg_lds[g * 128 + (m0 + r) * 16 + (lane & 15)] = acc[r];
    }
    __syncthreads();
    if (tid < 128) {
      const float hrv = hg_lds[tid] + bhh_lds[n16];
      const float hzv = hg_lds[128 + tid] + bhh_lds[16 + n16];
      const float hnv = hg_lds[256 + tid] + bhh_lds[32 + n16];
      const float r = 1.f / (1.f + __expf(-(xr + hrv)));
      const float z = 1.f / (1.f + __expf(-(xz + hzv)));
      const float nn = tanhf(xn + r * hnv);
      const float hnew = (1.f - z) * nn + z * h_my[tid];
      h_my[tid] = hnew;
      hs[((size_t)b8 * SEQ + t) * HID + wid * 16 + n16] = hnew;
    }
    __syncthreads();
    // publish new h slice as 32-bit packed bf16 pairs (native atomic width)
    if (tid < 64) {
      const int i0 = tid * 2;
      union { unsigned short s[2]; uint32_t u; } pk;
      pk.s[0] = f2bf(h_my[i0]);
      pk.s[1] = f2bf(h_my[i0 + 1]);
      uint32_t* dst =
          (uint32_t*)(wr_ + (i0 >> 4) * HID + wid * 16 + (i0 & 15));
      __hip_atomic_store(dst, pk.u, __ATOMIC_RELAXED,
                         __HIP_MEMORY_SCOPE_AGENT);
    }
    __threadfence();
    __syncthreads();
    if (tid == 0)
      __hip_atomic_store(flags + wid * 16, t + 1, __ATOMIC_RELEASE,
                         __HIP_MEMORY_SCOPE_AGENT);
    // prefetch next xg while we spin
    if (tid < 128 && t + 1 < SEQ) {
      const size_t xo = xoff0 + (size_t)(t + 1) * NG;
      xr = xg[xo]; xz = xg[xo + HID]; xn = xg[xo + 2 * HID];
    }
    if (tid < 64) {
      while (budget > 0) {
        int v = __hip_atomic_load(flags + myflag, __ATOMIC_ACQUIRE,
                                  __HIP_MEMORY_SCOPE_AGENT);
        if (__ballot(v >= t + 1) == ~0ULL) break;
        --budget;
        __builtin_amdgcn_s_sleep(2);
      }
    }
    __syncthreads();
  }
}

// ---------------- LayerNorm rows of 512 -> bf16 ------------------------------
__global__ __launch_bounds__(256) void ln_kernel(
    const float* __restrict__ hs, const float* __restrict__ gamma,
    const float* __restrict__ beta, unsigned short* __restrict__ y) {
  const int row = blockIdx.x * 4 + (threadIdx.x >> 6);
  const int lane = threadIdx.x & 63;
  const float* x = hs + (size_t)row * HID + lane * 8;
  float v[8];
  *(float4*)v = *(const float4*)x;
  *(float4*)(v + 4) = *(const float4*)(x + 4);
  float s = 0.f, q = 0.f;
#pragma unroll
  for (int j = 0; j < 8; ++j) { s += v[j]; q += v[j] * v[j]; }
#pragma unroll
  for (int off = 32; off > 0; off >>= 1) {
    s += __shfl_xor(s, off);
    q += __shfl_xor(q, off);
  }
  const float mu = s * (1.f / 512.f);
  const float is = rsqrtf(q * (1.f / 512.f) - mu * mu + LN_EPS);
  const float* gp = gamma + lane * 8;
  const float* bp = beta + lane * 8;
  union { unsigned short o[8]; uint4 u; } pk;
#pragma unroll
  for (int j = 0; j < 8; ++j) pk.o[j] = f2bf((v[j] - mu) * is * gp[j] + bp[j]);
  *(uint4*)(y + (size_t)row * HID + lane * 8) = pk.u;
}

// ---------------- launch -----------------------------------------------------
extern "C" void kernel_launch(void* const* d_in, const int* in_sizes, int n_in,
                              void* d_out, int out_size, void* d_ws,
                              size_t ws_size, hipStream_t stream) {
  const int* ids = (const int*)d_in[0];
  const float* emb = (const float*)d_in[1];
  const float* w_ih = (const float*)d_in[2];
  const float* w_hh = (const float*)d_in[3];
  const float* b_ih = (const float*)d_in[4];
  const float* b_hh = (const float*)d_in[5];
  const float* gamma = (const float*)d_in[6];
  const float* beta = (const float*)d_in[7];
  const float* head_w = (const float*)d_in[8];
  const float* head_b = (const float*)d_in[9];
  float* out = (float*)d_out;

  char* ws = (char*)d_ws;
  size_t off = 0;
  auto alloc = [&](size_t bytes) -> void* {
    void* p = ws + off;
    off = (off + bytes + 255) & ~(size_t)255;
    return p;
  };
  int* flags = (int*)alloc(GRU_WGS * 16 * sizeof(int));
  unsigned short* h_state = (unsigned short*)alloc(2 * 16 * HID * 2);
  unsigned short* A1 = (unsigned short*)alloc((size_t)NB * SEQ * HID * 2);
  unsigned short* wihb = (unsigned short*)alloc((size_t)NG * HID * 2);
  unsigned short* hwb = (unsigned short*)alloc((size_t)VOCAB * HID * 2);
  float* xg = (float*)alloc((size_t)NB * SEQ * NG * 4);
  float* hsb = (float*)alloc((size_t)NB * SEQ * HID * 4);
  unsigned short* yb = (unsigned short*)alloc((size_t)NB * SEQ * HID * 2);

  init_ws_kernel<<<64, 256, 0, stream>>>(h_state, flags);
  conv_bf16_kernel<<<(NG * HID / 4) / 256, 256, 0, stream>>>(w_ih, wihb,
                                                             NG * HID / 4);
  conv_bf16_kernel<<<(VOCAB * HID / 4) / 256, 256, 0, stream>>>(
      head_w, hwb, VOCAB * HID / 4);
  embed_kernel<<<NB * SEQ, 256, 0, stream>>>(ids, emb, A1);
  // xg = A1 * w_ih^T + b_ih : M=4096, N=1536  (grid 32*12=384, %8==0)
  gemm_bt_kernel<<<(NB * SEQ / BM) * (NG / BN), 256, 0, stream>>>(
      A1, wihb, b_ih, xg, NG, NG / BN);
  gru_kernel<<<GRU_WGS, 192, 0, stream>>>(xg, w_hh, b_hh, hsb, h_state, flags);
  ln_kernel<<<NB * SEQ / 4, 256, 0, stream>>>(hsb, gamma, beta, yb);
  // logits = y * head_w^T + head_b : M=4096, N=32000 (grid 32*250=8000, %8==0)
  gemm_bt_kernel<<<(NB * SEQ / BM) * (VOCAB / BN), 256, 0, stream>>>(
      yb, hwb, head_b, out, VOCAB, VOCAB / BN);
}

// Round 3
// 1979.710 us; speedup vs baseline: 2.0159x; 2.0159x over previous
//
#include <hip/hip_runtime.h>
#include <hip/hip_bf16.h>
#include <stdint.h>

#define VOCAB 32000
#define HID 512
#define NB 8
#define SEQ 512
#define NG 1536
#define LN_EPS 1e-5f
#define GRU_WGS 32
#define GRU_SPIN_BUDGET (1 << 20)

typedef short bf16x8 __attribute__((ext_vector_type(8)));
typedef float f32x4 __attribute__((ext_vector_type(4)));

__device__ __forceinline__ unsigned short f2bf(float f) {
  union { float f; uint32_t u; } c; c.f = f;
  return (unsigned short)((c.u + 0x7fffu + ((c.u >> 16) & 1u)) >> 16);
}

// ---------------- init workspace (every launch: h_state bufs=0, flags=0) ----
__global__ void init_ws_kernel(unsigned short* h_state, int* flags) {
  int i = blockIdx.x * 256 + threadIdx.x;
  if (i < 2 * 16 * HID) h_state[i] = 0;
  if (i < GRU_WGS * 16) flags[i] = 0;
}

// ---------------- fp32 -> bf16 bulk convert ---------------------------------
__global__ void conv_bf16_kernel(const float* __restrict__ in,
                                 unsigned short* __restrict__ out, int n4) {
  int i = blockIdx.x * 256 + threadIdx.x;
  if (i >= n4) return;
  const float4 v = ((const float4*)in)[i];
  ushort4 o;
  o.x = f2bf(v.x); o.y = f2bf(v.y); o.z = f2bf(v.z); o.w = f2bf(v.w);
  ((ushort4*)out)[i] = o;
}

// ---------------- embedding gather -> bf16 A matrix [4096][512] -------------
__global__ void embed_kernel(const int* __restrict__ ids,
                             const float* __restrict__ emb,
                             unsigned short* __restrict__ out) {
  int row = blockIdx.x;
  int id = ids[row];
  int c = threadIdx.x * 2;
  const float2 v = *(const float2*)(emb + (size_t)id * HID + c);
  ushort2 o; o.x = f2bf(v.x); o.y = f2bf(v.y);
  *(ushort2*)(out + (size_t)row * HID + c) = o;
}

// ---------------- bf16 GEMM: C[M][N] = A[M][K] * B[N][K]^T + bias -----------
// m97 structure: 128x128 tile, BK=32, 4 waves (2x2), 4x4 16x16x32 frags/wave,
// global_load_lds width=16 staging, XCD-chunked block swizzle (nwg%8==0).
#define BM 128
#define BN 128
#define BK 32

__global__ __launch_bounds__(256, 2) void gemm_bt_kernel(
    const unsigned short* __restrict__ A, const unsigned short* __restrict__ B,
    const float* __restrict__ bias, float* __restrict__ C, int N, int nbn) {
  __shared__ unsigned short a_lds[BM * BK];
  __shared__ unsigned short b_lds[BN * BK];
  const int nwg = gridDim.x;
  const int chunk = nwg >> 3;
  const int bid = blockIdx.x;
  const int sw = (bid & 7) * chunk + (bid >> 3);
  const int bm = sw / nbn, bn = sw % nbn;
  const int tid = threadIdx.x;
  const int lane = tid & 63, wid = tid >> 6;
  const int wm = wid >> 1, wn = wid & 1;

  f32x4 acc[4][4] = {};

  for (int kt = 0; kt < HID / BK; ++kt) {
    __syncthreads();
#pragma unroll
    for (int p = 0; p < 2; ++p) {
      const int flat = (p * 256 + tid) * 16;  // byte offset in 8KB tile
      const int row = flat >> 6;              // 64B per row (32 bf16)
      const int kb = flat & 63;
      const char* ga =
          (const char*)(A + ((size_t)(bm * BM + row) * HID + kt * BK)) + kb;
      const char* gb =
          (const char*)(B + ((size_t)(bn * BN + row) * HID + kt * BK)) + kb;
      char* la = (char*)a_lds + (size_t)(p * 256 + wid * 64) * 16;
      char* lb = (char*)b_lds + (size_t)(p * 256 + wid * 64) * 16;
      __builtin_amdgcn_global_load_lds(
          (const __attribute__((address_space(1))) void*)ga,
          (__attribute__((address_space(3))) void*)la, 16, 0, 0);
      __builtin_amdgcn_global_load_lds(
          (const __attribute__((address_space(1))) void*)gb,
          (__attribute__((address_space(3))) void*)lb, 16, 0, 0);
    }
    __syncthreads();
    bf16x8 af[4], bfr[4];
#pragma unroll
    for (int i = 0; i < 4; ++i) {
      af[i] = *(const bf16x8*)(a_lds + (wm * 64 + i * 16 + (lane & 15)) * BK +
                               (lane >> 4) * 8);
      bfr[i] = *(const bf16x8*)(b_lds + (wn * 64 + i * 16 + (lane & 15)) * BK +
                                (lane >> 4) * 8);
    }
#pragma unroll
    for (int i = 0; i < 4; ++i)
#pragma unroll
      for (int j = 0; j < 4; ++j)
        acc[i][j] =
            __builtin_amdgcn_mfma_f32_16x16x32_bf16(af[i], bfr[j], acc[i][j], 0, 0, 0);
  }
#pragma unroll
  for (int i = 0; i < 4; ++i) {
    const int mrow = bm * BM + wm * 64 + i * 16 + (lane >> 4) * 4;
#pragma unroll
    for (int j = 0; j < 4; ++j) {
      const int col = bn * BN + wn * 64 + j * 16 + (lane & 15);
      const float bv = bias[col];
#pragma unroll
      for (int r = 0; r < 4; ++r)
        C[(size_t)(mrow + r) * N + col] = acc[i][j][r] + bv;
    }
  }
}

// ---------------- persistent GRU scan ---------------------------------------
// 32 WGs x 192 threads (3 waves). WG w owns h indices [w*16, w*16+16).
// Wave g (=gate r/z/n) holds its 16 w_hh rows as bf16 MFMA B-frags in regs.
// h_state DOUBLE-BUFFERED (read buf[t&1], write buf[(t+1)&1]).
// Protocol: ALL cross-WG traffic (h_state, flags) uses RELAXED agent-scope
// ops, which bypass L1/L2 and resolve at the shared LLC — no acquire/release
// cache maintenance (buffer_inv/buffer_wbl2) anywhere. Ordering:
//   h stores (sc1, to LLC) -> __syncthreads (drains vmcnt(0) per wave, so
//   stores are LLC-visible) -> relaxed flag store -> consumers poll flags
//   (relaxed) -> consumers load h (relaxed, issued after barrier).
__global__ __launch_bounds__(192, 1) void gru_kernel(
    const float* __restrict__ xg, const float* __restrict__ w_hh,
    const float* __restrict__ b_hh, float* __restrict__ hs,
    unsigned short* h_state, int* flags) {
  const int wid = blockIdx.x;
  const int tid = threadIdx.x;
  const int lane = tid & 63;
  const int g = tid >> 6;

  __shared__ float hg_lds[3 * 128];
  __shared__ float bhh_lds[48];

  // pack weights into MFMA B-fragments (registers), once
  bf16x8 wf[16];
  {
    const int row = g * HID + wid * 16 + (lane & 15);
    const float* wr = w_hh + (size_t)row * HID + (lane >> 4) * 8;
#pragma unroll
    for (int kk = 0; kk < 16; ++kk) {
      float4 f0 = *(const float4*)(wr + kk * 32);
      float4 f1 = *(const float4*)(wr + kk * 32 + 4);
      bf16x8 v;
      v[0] = (short)f2bf(f0.x); v[1] = (short)f2bf(f0.y);
      v[2] = (short)f2bf(f0.z); v[3] = (short)f2bf(f0.w);
      v[4] = (short)f2bf(f1.x); v[5] = (short)f2bf(f1.y);
      v[6] = (short)f2bf(f1.z); v[7] = (short)f2bf(f1.w);
      wf[kk] = v;
    }
  }
  if (tid < 48) bhh_lds[tid] = b_hh[(tid >> 4) * HID + wid * 16 + (tid & 15)];
  __syncthreads();

  const int abase = (lane & 15) * HID + (lane >> 4) * 8;  // bf16-elem index
  const bool realrow = (lane & 15) < 8;  // batches 8..15 are structural zeros
  const int myflag = (lane & 31) * 16;
  const int b8 = tid >> 4, n16 = tid & 15;
  const size_t xoff0 = (size_t)b8 * SEQ * NG + wid * 16 + n16;

  float xr = 0.f, xz = 0.f, xn = 0.f;
  if (tid < 128) {
    xr = xg[xoff0];
    xz = xg[xoff0 + HID];
    xn = xg[xoff0 + 2 * HID];
  }
  float hprev = 0.f;  // this thread's own h (fp32, register-resident)
  int budget = GRU_SPIN_BUDGET;

  for (int t = 0; t < SEQ; ++t) {
    const unsigned short* rd = h_state + (size_t)(t & 1) * (16 * HID);
    unsigned short* wr_ = h_state + (size_t)((t + 1) & 1) * (16 * HID);

    // issue the 16 real h-row loads (independent), rows 8..15 are zeros
    uint64_t hb[32];
#pragma unroll
    for (int kk = 0; kk < 32; ++kk) hb[kk] = 0;
    if (realrow) {
#pragma unroll
      for (int kk = 0; kk < 16; ++kk) {
        const uint64_t* ap = (const uint64_t*)(rd + abase + kk * 32);
        hb[2 * kk] =
            __hip_atomic_load(ap, __ATOMIC_RELAXED, __HIP_MEMORY_SCOPE_AGENT);
        hb[2 * kk + 1] = __hip_atomic_load(ap + 1, __ATOMIC_RELAXED,
                                           __HIP_MEMORY_SCOPE_AGENT);
      }
    }
    f32x4 acc = {0.f, 0.f, 0.f, 0.f};
#pragma unroll
    for (int kk = 0; kk < 16; ++kk) {
      union { uint64_t u[2]; bf16x8 v; } cv;
      cv.u[0] = hb[2 * kk]; cv.u[1] = hb[2 * kk + 1];
      acc = __builtin_amdgcn_mfma_f32_16x16x32_bf16(cv.v, wf[kk], acc, 0, 0, 0);
    }
    if (lane < 32) {  // real batches m=0..7 live in lanes 0..31
      const int m0 = (lane >> 4) * 4;
#pragma unroll
      for (int r = 0; r < 4; ++r)
        hg_lds[g * 128 + (m0 + r) * 16 + (lane & 15)] = acc[r];
    }
    __syncthreads();
    if (tid < 128) {
      const float hrv = hg_lds[tid] + bhh_lds[n16];
      const float hzv = hg_lds[128 + tid] + bhh_lds[16 + n16];
      const float hnv = hg_lds[256 + tid] + bhh_lds[32 + n16];
      const float r = 1.f / (1.f + __expf(-(xr + hrv)));
      const float z = 1.f / (1.f + __expf(-(xz + hzv)));
      const float a = xn + r * hnv;
      const float e2 = __expf(-2.f * fabsf(a));
      const float nn = copysignf((1.f - e2) / (1.f + e2), a);
      const float hnew = (1.f - z) * nn + z * hprev;
      hprev = hnew;
      hs[((size_t)b8 * SEQ + t) * HID + wid * 16 + n16] = hnew;
      // publish bf16 h: pack with the odd neighbor, even lane stores 32-bit
      const float hnb = __shfl_down(hnew, 1);
      if ((n16 & 1) == 0) {
        union { unsigned short s[2]; uint32_t u; } pk;
        pk.s[0] = f2bf(hnew); pk.s[1] = f2bf(hnb);
        uint32_t* dst = (uint32_t*)(wr_ + b8 * HID + wid * 16 + n16);
        __hip_atomic_store(dst, pk.u, __ATOMIC_RELAXED,
                           __HIP_MEMORY_SCOPE_AGENT);
      }
    }
    __syncthreads();  // drains vmcnt(0): h publishes are LLC-visible
    if (tid == 0)
      __hip_atomic_store(flags + wid * 16, t + 1, __ATOMIC_RELAXED,
                         __HIP_MEMORY_SCOPE_AGENT);
    // prefetch next xg while we spin
    if (tid < 128 && t + 1 < SEQ) {
      const size_t xo = xoff0 + (size_t)(t + 1) * NG;
      xr = xg[xo]; xz = xg[xo + HID]; xn = xg[xo + 2 * HID];
    }
    if (tid < 64) {
      while (budget > 0) {
        int v = __hip_atomic_load(flags + myflag, __ATOMIC_RELAXED,
                                  __HIP_MEMORY_SCOPE_AGENT);
        if (__ballot(v >= t + 1) == ~0ULL) break;
        --budget;
        __builtin_amdgcn_s_sleep(1);
      }
    }
    __syncthreads();
  }
}

// ---------------- LayerNorm rows of 512 -> bf16 ------------------------------
__global__ __launch_bounds__(256) void ln_kernel(
    const float* __restrict__ hs, const float* __restrict__ gamma,
    const float* __restrict__ beta, unsigned short* __restrict__ y) {
  const int row = blockIdx.x * 4 + (threadIdx.x >> 6);
  const int lane = threadIdx.x & 63;
  const float* x = hs + (size_t)row * HID + lane * 8;
  float v[8];
  *(float4*)v = *(const float4*)x;
  *(float4*)(v + 4) = *(const float4*)(x + 4);
  float s = 0.f, q = 0.f;
#pragma unroll
  for (int j = 0; j < 8; ++j) { s += v[j]; q += v[j] * v[j]; }
#pragma unroll
  for (int off = 32; off > 0; off >>= 1) {
    s += __shfl_xor(s, off);
    q += __shfl_xor(q, off);
  }
  const float mu = s * (1.f / 512.f);
  const float is = rsqrtf(q * (1.f / 512.f) - mu * mu + LN_EPS);
  const float* gp = gamma + lane * 8;
  const float* bp = beta + lane * 8;
  union { unsigned short o[8]; uint4 u; } pk;
#pragma unroll
  for (int j = 0; j < 8; ++j) pk.o[j] = f2bf((v[j] - mu) * is * gp[j] + bp[j]);
  *(uint4*)(y + (size_t)row * HID + lane * 8) = pk.u;
}

// ---------------- launch -----------------------------------------------------
extern "C" void kernel_launch(void* const* d_in, const int* in_sizes, int n_in,
                              void* d_out, int out_size, void* d_ws,
                              size_t ws_size, hipStream_t stream) {
  const int* ids = (const int*)d_in[0];
  const float* emb = (const float*)d_in[1];
  const float* w_ih = (const float*)d_in[2];
  const float* w_hh = (const float*)d_in[3];
  const float* b_ih = (const float*)d_in[4];
  const float* b_hh = (const float*)d_in[5];
  const float* gamma = (const float*)d_in[6];
  const float* beta = (const float*)d_in[7];
  const float* head_w = (const float*)d_in[8];
  const float* head_b = (const float*)d_in[9];
  float* out = (float*)d_out;

  char* ws = (char*)d_ws;
  size_t off = 0;
  auto alloc = [&](size_t bytes) -> void* {
    void* p = ws + off;
    off = (off + bytes + 255) & ~(size_t)255;
    return p;
  };
  int* flags = (int*)alloc(GRU_WGS * 16 * sizeof(int));
  unsigned short* h_state = (unsigned short*)alloc(2 * 16 * HID * 2);
  unsigned short* A1 = (unsigned short*)alloc((size_t)NB * SEQ * HID * 2);
  unsigned short* wihb = (unsigned short*)alloc((size_t)NG * HID * 2);
  unsigned short* hwb = (unsigned short*)alloc((size_t)VOCAB * HID * 2);
  float* xg = (float*)alloc((size_t)NB * SEQ * NG * 4);
  float* hsb = (float*)alloc((size_t)NB * SEQ * HID * 4);
  unsigned short* yb = (unsigned short*)alloc((size_t)NB * SEQ * HID * 2);

  init_ws_kernel<<<64, 256, 0, stream>>>(h_state, flags);
  conv_bf16_kernel<<<(NG * HID / 4) / 256, 256, 0, stream>>>(w_ih, wihb,
                                                             NG * HID / 4);
  conv_bf16_kernel<<<(VOCAB * HID / 4) / 256, 256, 0, stream>>>(
      head_w, hwb, VOCAB * HID / 4);
  embed_kernel<<<NB * SEQ, 256, 0, stream>>>(ids, emb, A1);
  // xg = A1 * w_ih^T + b_ih : M=4096, N=1536  (grid 32*12=384, %8==0)
  gemm_bt_kernel<<<(NB * SEQ / BM) * (NG / BN), 256, 0, stream>>>(
      A1, wihb, b_ih, xg, NG, NG / BN);
  gru_kernel<<<GRU_WGS, 192, 0, stream>>>(xg, w_hh, b_hh, hsb, h_state, flags);
  ln_kernel<<<NB * SEQ / 4, 256, 0, stream>>>(hsb, gamma, beta, yb);
  // logits = y * head_w^T + head_b : M=4096, N=32000 (grid 32*250=8000, %8==0)
  gemm_bt_kernel<<<(NB * SEQ / BM) * (VOCAB / BN), 256, 0, stream>>>(
      yb, hwb, head_b, out, VOCAB, VOCAB / BN);
}